// Round 3
// baseline (302.131 us; speedup 1.0000x reference)
//
#include <hip/hip_runtime.h>

#define SS 2048
#define DD 64
#define S2 0.18033688011112042f   // (1/sqrt(64)) * log2(e)

typedef __attribute__((ext_vector_type(4))) float f32x4;
typedef __attribute__((ext_vector_type(8))) short bfx8;
typedef __attribute__((ext_vector_type(4))) short bfx4;

__device__ __forceinline__ short f2bf(float f) {
    unsigned u = __builtin_bit_cast(unsigned, f);
    u += 0x7fffu + ((u >> 16) & 1u);   // RTNE
    return (short)(u >> 16);
}
__device__ __forceinline__ bfx8 pack8(f32x4 a, f32x4 b) {
    bfx8 r;
    r[0] = f2bf(a[0]); r[1] = f2bf(a[1]); r[2] = f2bf(a[2]); r[3] = f2bf(a[3]);
    r[4] = f2bf(b[0]); r[5] = f2bf(b[1]); r[6] = f2bf(b[2]); r[7] = f2bf(b[3]);
    return r;
}

__global__ __launch_bounds__(256, 4) void pattn_kernel(
    const float* __restrict__ q, const float* __restrict__ k,
    const float* __restrict__ v, float* __restrict__ out,
    float* __restrict__ attn)
{
    const int bh  = blockIdx.x >> 5;   // 0..31 (B*H)
    const int qt  = blockIdx.x & 31;   // q tile of 64 rows
    const int tid = threadIdx.x;
    const int wid = tid >> 6, lane = tid & 63;
    const int c = lane & 15, g = lane >> 4;

    const long hoff = (long)bh * SS * DD;
    const int  qrow = qt * 64 + wid * 16 + c;   // this lane's q row

    __shared__ __align__(16) short Kl[128][72];    // [key][d]   18432 B
    __shared__ __align__(16) short Vt[64][136];    // [d][key]   17408 B
    __shared__ __align__(16) short Wl[4][16][40];  // per-wave [q][key32] 5120 B

    // Q fragment (B-operand of swapped QK^T): Q[qrow][8g..], [32+8g..]
    bfx8 bq0, bq1;
    {
        const float* qp = q + hoff + (long)qrow * DD + 8 * g;
        f32x4 x0 = *(const f32x4*)(qp);
        f32x4 x1 = *(const f32x4*)(qp + 4);
        f32x4 x2 = *(const f32x4*)(qp + 32);
        f32x4 x3 = *(const f32x4*)(qp + 36);
        bq0 = pack8(x0, x1);
        bq1 = pack8(x2, x3);
    }

    auto stageK = [&](int k0) {
        const int key = tid >> 1, dh = (tid & 1) << 5;
        const float* kp = k + hoff + (long)(k0 + key) * DD + dh;
        f32x4 a0 = *(const f32x4*)(kp);
        f32x4 a1 = *(const f32x4*)(kp + 4);
        f32x4 a2 = *(const f32x4*)(kp + 8);
        f32x4 a3 = *(const f32x4*)(kp + 12);
        f32x4 a4 = *(const f32x4*)(kp + 16);
        f32x4 a5 = *(const f32x4*)(kp + 20);
        f32x4 a6 = *(const f32x4*)(kp + 24);
        f32x4 a7 = *(const f32x4*)(kp + 28);
        *(bfx8*)&Kl[key][dh + 0]  = pack8(a0, a1);
        *(bfx8*)&Kl[key][dh + 8]  = pack8(a2, a3);
        *(bfx8*)&Kl[key][dh + 16] = pack8(a4, a5);
        *(bfx8*)&Kl[key][dh + 24] = pack8(a6, a7);
    };

    auto stageV = [&](int k0) {
        const int kq = (tid & 31) * 4, dg = (tid >> 5) * 8;
        const float* vp = v + hoff + (long)(k0 + kq) * DD + dg;
        f32x4 r0a = *(const f32x4*)(vp),        r0b = *(const f32x4*)(vp + 4);
        f32x4 r1a = *(const f32x4*)(vp + DD),   r1b = *(const f32x4*)(vp + DD + 4);
        f32x4 r2a = *(const f32x4*)(vp + 2*DD), r2b = *(const f32x4*)(vp + 2*DD + 4);
        f32x4 r3a = *(const f32x4*)(vp + 3*DD), r3b = *(const f32x4*)(vp + 3*DD + 4);
        #pragma unroll
        for (int d = 0; d < 4; ++d) {
            bfx4 w;
            w[0] = f2bf(r0a[d]); w[1] = f2bf(r1a[d]);
            w[2] = f2bf(r2a[d]); w[3] = f2bf(r3a[d]);
            *(bfx4*)&Vt[dg + d][kq] = w;
        }
        #pragma unroll
        for (int d = 0; d < 4; ++d) {
            bfx4 w;
            w[0] = f2bf(r0b[d]); w[1] = f2bf(r1b[d]);
            w[2] = f2bf(r2b[d]); w[3] = f2bf(r3b[d]);
            *(bfx4*)&Vt[dg + 4 + d][kq] = w;
        }
    };

    // ---------------- pass 1: row sums of exp2(score*S2) ----------------
    float lsum = 0.f;
    for (int k0 = 0; k0 < SS; k0 += 128) {
        stageK(k0);
        __syncthreads();
        #pragma unroll
        for (int T = 0; T < 8; ++T) {
            bfx8 kb0 = *(const bfx8*)&Kl[T * 16 + c][8 * g];
            bfx8 kb1 = *(const bfx8*)&Kl[T * 16 + c][32 + 8 * g];
            f32x4 s = {0.f, 0.f, 0.f, 0.f};
            s = __builtin_amdgcn_mfma_f32_16x16x32_bf16(kb0, bq0, s, 0, 0, 0);
            s = __builtin_amdgcn_mfma_f32_16x16x32_bf16(kb1, bq1, s, 0, 0, 0);
            lsum += __builtin_amdgcn_exp2f(s[0] * S2);
            lsum += __builtin_amdgcn_exp2f(s[1] * S2);
            lsum += __builtin_amdgcn_exp2f(s[2] * S2);
            lsum += __builtin_amdgcn_exp2f(s[3] * S2);
        }
        __syncthreads();
    }
    lsum += __shfl_xor(lsum, 16, 64);
    lsum += __shfl_xor(lsum, 32, 64);
    const float invl = 1.0f / lsum;

    // ---------------- pass 2: attn write + PV ----------------
    f32x4 acc[4];
    #pragma unroll
    for (int i = 0; i < 4; ++i) acc[i] = (f32x4){0.f, 0.f, 0.f, 0.f};

    float* attnb = attn + (long)bh * SS * SS + (long)qrow * SS;

    for (int k0 = 0; k0 < SS; k0 += 128) {
        stageK(k0);
        stageV(k0);
        __syncthreads();
        #pragma unroll
        for (int G = 0; G < 4; ++G) {
            #pragma unroll
            for (int t = 0; t < 2; ++t) {
                const int kb = G * 32 + t * 16;
                bfx8 kb0 = *(const bfx8*)&Kl[kb + c][8 * g];
                bfx8 kb1 = *(const bfx8*)&Kl[kb + c][32 + 8 * g];
                f32x4 s = {0.f, 0.f, 0.f, 0.f};
                s = __builtin_amdgcn_mfma_f32_16x16x32_bf16(kb0, bq0, s, 0, 0, 0);
                s = __builtin_amdgcn_mfma_f32_16x16x32_bf16(kb1, bq1, s, 0, 0, 0);
                f32x4 w;
                w[0] = __builtin_amdgcn_exp2f(s[0] * S2) * invl;
                w[1] = __builtin_amdgcn_exp2f(s[1] * S2) * invl;
                w[2] = __builtin_amdgcn_exp2f(s[2] * S2) * invl;
                w[3] = __builtin_amdgcn_exp2f(s[3] * S2) * invl;
                *(f32x4*)&attnb[k0 + kb + 4 * g] = w;   // 4 consecutive keys
                bfx4 wp = { f2bf(w[0]), f2bf(w[1]), f2bf(w[2]), f2bf(w[3]) };
                *(bfx4*)&Wl[wid][c][t * 16 + 4 * g] = wp;
            }
            // PV over this 32-key group (wave-private Wl: lgkmcnt-ordered, no barrier)
            bfx8 wb = *(const bfx8*)&Wl[wid][c][8 * g];
            #pragma unroll
            for (int ds = 0; ds < 4; ++ds) {
                bfx8 va = *(const bfx8*)&Vt[ds * 16 + c][G * 32 + 8 * g];
                acc[ds] = __builtin_amdgcn_mfma_f32_16x16x32_bf16(va, wb, acc[ds], 0, 0, 0);
            }
        }
        __syncthreads();
    }

    // ---------------- row-norm preconditioning + output ----------------
    float ssq = 0.f;
    #pragma unroll
    for (int ds = 0; ds < 4; ++ds)
        #pragma unroll
        for (int r = 0; r < 4; ++r)
            ssq += acc[ds][r] * acc[ds][r];
    ssq += __shfl_xor(ssq, 16, 64);
    ssq += __shfl_xor(ssq, 32, 64);
    const float inv = 1.0f / (sqrtf(ssq) + 1e-8f);

    float* op = out + hoff + (long)qrow * DD;
    #pragma unroll
    for (int ds = 0; ds < 4; ++ds) {
        f32x4 o;
        o[0] = acc[ds][0] * inv; o[1] = acc[ds][1] * inv;
        o[2] = acc[ds][2] * inv; o[3] = acc[ds][3] * inv;
        *(f32x4*)&op[ds * 16 + 4 * g] = o;
    }
}

extern "C" void kernel_launch(void* const* d_in, const int* in_sizes, int n_in,
                              void* d_out, int out_size, void* d_ws, size_t ws_size,
                              hipStream_t stream) {
    const float* q = (const float*)d_in[0];
    const float* k = (const float*)d_in[1];
    const float* v = (const float*)d_in[2];
    float* out  = (float*)d_out;
    float* attn = out + (long)2 * 16 * SS * DD;   // second tuple element
    dim3 grid(1024), block(256);
    hipLaunchKernelGGL(pattn_kernel, grid, block, 0, stream, q, k, v, out, attn);
}

// Round 4
// 265.137 us; speedup vs baseline: 1.1395x; 1.1395x over previous
//
#include <hip/hip_runtime.h>

#define SS 2048
#define DD 64
#define S2 0.18033688011112042f   // (1/sqrt(64)) * log2(e)

typedef __attribute__((ext_vector_type(4))) float f32x4;
typedef __attribute__((ext_vector_type(8))) short bfx8;
typedef __attribute__((ext_vector_type(4))) short bfx4;

__device__ __forceinline__ short f2bf(float f) {
    unsigned u = __builtin_bit_cast(unsigned, f);
    u += 0x7fffu + ((u >> 16) & 1u);   // RTNE
    return (short)(u >> 16);
}
__device__ __forceinline__ bfx8 pack8(f32x4 a, f32x4 b) {
    bfx8 r;
    r[0] = f2bf(a[0]); r[1] = f2bf(a[1]); r[2] = f2bf(a[2]); r[3] = f2bf(a[3]);
    r[4] = f2bf(b[0]); r[5] = f2bf(b[1]); r[6] = f2bf(b[2]); r[7] = f2bf(b[3]);
    return r;
}
__device__ __forceinline__ float bf2f(short s) {
    unsigned u = ((unsigned)(unsigned short)s) << 16;
    return __builtin_bit_cast(float, u);
}

__global__ __launch_bounds__(256) void pattn_kernel(
    const float* __restrict__ q, const float* __restrict__ k,
    const float* __restrict__ v, float* __restrict__ out,
    float* __restrict__ attn)
{
    const int bh  = blockIdx.x >> 5;   // 0..31 (B*H)
    const int qt  = blockIdx.x & 31;   // q tile of 64 rows
    const int tid = threadIdx.x;
    const int wid = tid >> 6, lane = tid & 63;
    const int c = lane & 15, g = lane >> 4;

    const long hoff = (long)bh * SS * DD;
    const int  qrow = qt * 64 + wid * 16 + c;   // this lane's q row

    __shared__ __align__(16) short Kl[128][72];     // [key][d]        18432 B
    __shared__ __align__(16) short Vt[64][136];     // [d][key]        17408 B
    __shared__ __align__(16) short Wc[4][16][136];  // wave [q][key128] 17408 B

    // Q fragment (B-operand of swapped QK^T): Q[qrow][8g..], [32+8g..]
    bfx8 bq0, bq1;
    {
        const float* qp = q + hoff + (long)qrow * DD + 8 * g;
        f32x4 x0 = *(const f32x4*)(qp);
        f32x4 x1 = *(const f32x4*)(qp + 4);
        f32x4 x2 = *(const f32x4*)(qp + 32);
        f32x4 x3 = *(const f32x4*)(qp + 36);
        bq0 = pack8(x0, x1);
        bq1 = pack8(x2, x3);
    }

    auto stageK = [&](int k0) {
        const int key = tid >> 1, dh = (tid & 1) << 5;
        const float* kp = k + hoff + (long)(k0 + key) * DD + dh;
        f32x4 a0 = *(const f32x4*)(kp);
        f32x4 a1 = *(const f32x4*)(kp + 4);
        f32x4 a2 = *(const f32x4*)(kp + 8);
        f32x4 a3 = *(const f32x4*)(kp + 12);
        f32x4 a4 = *(const f32x4*)(kp + 16);
        f32x4 a5 = *(const f32x4*)(kp + 20);
        f32x4 a6 = *(const f32x4*)(kp + 24);
        f32x4 a7 = *(const f32x4*)(kp + 28);
        *(bfx8*)&Kl[key][dh + 0]  = pack8(a0, a1);
        *(bfx8*)&Kl[key][dh + 8]  = pack8(a2, a3);
        *(bfx8*)&Kl[key][dh + 16] = pack8(a4, a5);
        *(bfx8*)&Kl[key][dh + 24] = pack8(a6, a7);
    };

    auto stageV = [&](int k0) {
        const int kq = (tid & 31) * 4, dg = (tid >> 5) * 8;
        const float* vp = v + hoff + (long)(k0 + kq) * DD + dg;
        f32x4 r0a = *(const f32x4*)(vp),        r0b = *(const f32x4*)(vp + 4);
        f32x4 r1a = *(const f32x4*)(vp + DD),   r1b = *(const f32x4*)(vp + DD + 4);
        f32x4 r2a = *(const f32x4*)(vp + 2*DD), r2b = *(const f32x4*)(vp + 2*DD + 4);
        f32x4 r3a = *(const f32x4*)(vp + 3*DD), r3b = *(const f32x4*)(vp + 3*DD + 4);
        #pragma unroll
        for (int d = 0; d < 4; ++d) {
            bfx4 w;
            w[0] = f2bf(r0a[d]); w[1] = f2bf(r1a[d]);
            w[2] = f2bf(r2a[d]); w[3] = f2bf(r3a[d]);
            *(bfx4*)&Vt[dg + d][kq] = w;
        }
        #pragma unroll
        for (int d = 0; d < 4; ++d) {
            bfx4 w;
            w[0] = f2bf(r0b[d]); w[1] = f2bf(r1b[d]);
            w[2] = f2bf(r2b[d]); w[3] = f2bf(r3b[d]);
            *(bfx4*)&Vt[dg + 4 + d][kq] = w;
        }
    };

    // ---------------- pass 1: row sums of exp2(score*S2) ----------------
    float lsum = 0.f;
    for (int k0 = 0; k0 < SS; k0 += 128) {
        stageK(k0);
        __syncthreads();
        #pragma unroll
        for (int T = 0; T < 8; ++T) {
            bfx8 kb0 = *(const bfx8*)&Kl[T * 16 + c][8 * g];
            bfx8 kb1 = *(const bfx8*)&Kl[T * 16 + c][32 + 8 * g];
            f32x4 s = {0.f, 0.f, 0.f, 0.f};
            s = __builtin_amdgcn_mfma_f32_16x16x32_bf16(kb0, bq0, s, 0, 0, 0);
            s = __builtin_amdgcn_mfma_f32_16x16x32_bf16(kb1, bq1, s, 0, 0, 0);
            lsum += __builtin_amdgcn_exp2f(s[0] * S2);
            lsum += __builtin_amdgcn_exp2f(s[1] * S2);
            lsum += __builtin_amdgcn_exp2f(s[2] * S2);
            lsum += __builtin_amdgcn_exp2f(s[3] * S2);
        }
        __syncthreads();
    }
    lsum += __shfl_xor(lsum, 16, 64);
    lsum += __shfl_xor(lsum, 32, 64);
    const float invl = 1.0f / lsum;

    // ---------------- pass 2: W (LDS bf16) + PV + coalesced attn store ----------------
    f32x4 acc[4];
    #pragma unroll
    for (int i = 0; i < 4; ++i) acc[i] = (f32x4){0.f, 0.f, 0.f, 0.f};

    float* attnw = attn + (long)bh * SS * SS + (long)(qt * 64 + wid * 16) * SS;

    for (int k0 = 0; k0 < SS; k0 += 128) {
        stageK(k0);
        stageV(k0);
        __syncthreads();
        #pragma unroll
        for (int G = 0; G < 4; ++G) {
            #pragma unroll
            for (int t = 0; t < 2; ++t) {
                const int kb = G * 32 + t * 16;
                bfx8 kb0 = *(const bfx8*)&Kl[kb + c][8 * g];
                bfx8 kb1 = *(const bfx8*)&Kl[kb + c][32 + 8 * g];
                f32x4 s = {0.f, 0.f, 0.f, 0.f};
                s = __builtin_amdgcn_mfma_f32_16x16x32_bf16(kb0, bq0, s, 0, 0, 0);
                s = __builtin_amdgcn_mfma_f32_16x16x32_bf16(kb1, bq1, s, 0, 0, 0);
                bfx4 wp;
                wp[0] = f2bf(__builtin_amdgcn_exp2f(s[0] * S2) * invl);
                wp[1] = f2bf(__builtin_amdgcn_exp2f(s[1] * S2) * invl);
                wp[2] = f2bf(__builtin_amdgcn_exp2f(s[2] * S2) * invl);
                wp[3] = f2bf(__builtin_amdgcn_exp2f(s[3] * S2) * invl);
                *(bfx4*)&Wc[wid][c][kb + 4 * g] = wp;
            }
            // PV over this 32-key group (wave-private Wc: lgkmcnt-ordered, no barrier)
            bfx8 wb = *(const bfx8*)&Wc[wid][c][G * 32 + 8 * g];
            #pragma unroll
            for (int ds = 0; ds < 4; ++ds) {
                bfx8 va = *(const bfx8*)&Vt[ds * 16 + c][G * 32 + 8 * g];
                acc[ds] = __builtin_amdgcn_mfma_f32_16x16x32_bf16(va, wb, acc[ds], 0, 0, 0);
            }
        }
        __syncthreads();   // all waves done with Kl/Vt (next iter restages)

        // coalesced attn emit: per iteration 4 rows x 512B contiguous bursts
        {
            const int col8 = (lane & 15) * 8;        // 8 consecutive keys
            #pragma unroll
            for (int rg = 0; rg < 4; ++rg) {
                const int r = rg * 4 + (lane >> 4);
                bfx8 w8 = *(const bfx8*)&Wc[wid][r][col8];
                f32x4 lo, hi;
                lo[0] = bf2f(w8[0]); lo[1] = bf2f(w8[1]);
                lo[2] = bf2f(w8[2]); lo[3] = bf2f(w8[3]);
                hi[0] = bf2f(w8[4]); hi[1] = bf2f(w8[5]);
                hi[2] = bf2f(w8[6]); hi[3] = bf2f(w8[7]);
                float* dst = attnw + (long)r * SS + k0 + col8;
                __builtin_nontemporal_store(lo, (f32x4*)dst);
                __builtin_nontemporal_store(hi, (f32x4*)(dst + 4));
            }
        }
    }

    // ---------------- row-norm preconditioning + output ----------------
    float ssq = 0.f;
    #pragma unroll
    for (int ds = 0; ds < 4; ++ds)
        #pragma unroll
        for (int r = 0; r < 4; ++r)
            ssq += acc[ds][r] * acc[ds][r];
    ssq += __shfl_xor(ssq, 16, 64);
    ssq += __shfl_xor(ssq, 32, 64);
    const float inv = 1.0f / (sqrtf(ssq) + 1e-8f);

    float* op = out + hoff + (long)qrow * DD;
    #pragma unroll
    for (int ds = 0; ds < 4; ++ds) {
        f32x4 o;
        o[0] = acc[ds][0] * inv; o[1] = acc[ds][1] * inv;
        o[2] = acc[ds][2] * inv; o[3] = acc[ds][3] * inv;
        *(f32x4*)&op[ds * 16 + 4 * g] = o;
    }
}

extern "C" void kernel_launch(void* const* d_in, const int* in_sizes, int n_in,
                              void* d_out, int out_size, void* d_ws, size_t ws_size,
                              hipStream_t stream) {
    const float* q = (const float*)d_in[0];
    const float* k = (const float*)d_in[1];
    const float* v = (const float*)d_in[2];
    float* out  = (float*)d_out;
    float* attn = out + (long)2 * 16 * SS * DD;   // second tuple element
    dim3 grid(1024), block(256);
    hipLaunchKernelGGL(pattn_kernel, grid, block, 0, stream, q, k, v, out, attn);
}